// Round 1
// baseline (4997.544 us; speedup 1.0000x reference)
//
#include <hip/hip_runtime.h>
#include <cmath>

#define TSEQ 4096
#define NB   32
#define DIM  256

// ---------------------------------------------------------------------------
// K1: out[r,:] = X[b,t,:] @ Wx^T + (Wx_b + Wh_b), where r = t*32 + b
// Tiles: BM=64, BN=64, BK=32; 256 threads; 4x4 micro-tile.
// A/B staged transposed in LDS (padded stride 68) so micro reads are b128.
// ---------------------------------------------------------------------------
__global__ __launch_bounds__(256) void k1_xproj(
    const float* __restrict__ X, const float* __restrict__ Wx,
    const float* __restrict__ bx, const float* __restrict__ bh,
    float* __restrict__ out)
{
    __shared__ __align__(16) float As[32][68];
    __shared__ __align__(16) float Bs[32][68];
    const int tid = threadIdx.x;
    const int r0 = blockIdx.x * 64;
    const int n0 = blockIdx.y * 64;
    const int tm = tid >> 4, tn = tid & 15;
    const int lr = tid >> 2;
    const int lk = (tid & 3) * 8;

    const int rg = r0 + lr;
    const float* arow = X + ((size_t)(rg & 31) * TSEQ + (size_t)(rg >> 5)) * DIM;
    const float* brow = Wx + (size_t)(n0 + lr) * DIM;

    float acc[4][4] = {};

    for (int k0 = 0; k0 < DIM; k0 += 32) {
        float4 a0 = *(const float4*)(arow + k0 + lk);
        float4 a1 = *(const float4*)(arow + k0 + lk + 4);
        float4 b0 = *(const float4*)(brow + k0 + lk);
        float4 b1 = *(const float4*)(brow + k0 + lk + 4);
        __syncthreads();
        As[lk+0][lr]=a0.x; As[lk+1][lr]=a0.y; As[lk+2][lr]=a0.z; As[lk+3][lr]=a0.w;
        As[lk+4][lr]=a1.x; As[lk+5][lr]=a1.y; As[lk+6][lr]=a1.z; As[lk+7][lr]=a1.w;
        Bs[lk+0][lr]=b0.x; Bs[lk+1][lr]=b0.y; Bs[lk+2][lr]=b0.z; Bs[lk+3][lr]=b0.w;
        Bs[lk+4][lr]=b1.x; Bs[lk+5][lr]=b1.y; Bs[lk+6][lr]=b1.z; Bs[lk+7][lr]=b1.w;
        __syncthreads();
        #pragma unroll
        for (int k = 0; k < 32; ++k) {
            float4 av = *(const float4*)&As[k][4*tm];
            float4 bv = *(const float4*)&Bs[k][4*tn];
            float avv[4] = {av.x, av.y, av.z, av.w};
            float bvv[4] = {bv.x, bv.y, bv.z, bv.w};
            #pragma unroll
            for (int i = 0; i < 4; ++i)
                #pragma unroll
                for (int j = 0; j < 4; ++j)
                    acc[i][j] = fmaf(avv[i], bvv[j], acc[i][j]);
        }
    }

    float4 bxa = *(const float4*)(bx + n0 + 4*tn);
    float4 bha = *(const float4*)(bh + n0 + 4*tn);
    float bias[4] = {bxa.x + bha.x, bxa.y + bha.y, bxa.z + bha.z, bxa.w + bha.w};
    #pragma unroll
    for (int i = 0; i < 4; ++i) {
        size_t r = (size_t)(r0 + 4*tm + i);
        float4 o = make_float4(acc[i][0] + bias[0], acc[i][1] + bias[1],
                               acc[i][2] + bias[2], acc[i][3] + bias[3]);
        *(float4*)(out + r*DIM + n0 + 4*tn) = o;
    }
}

// ---------------------------------------------------------------------------
// K2: sequential recurrence, in-place on d_out.
// One WG (256 threads = 4 waves) per batch chain. Wave q owns k in [64q,64q+64).
// Lane holds Wh rows 4*lane..4*lane+3 over its k-slice: 256 VGPRs of weights.
// Per step: uniform-address (broadcast) b128 LDS reads of h, 256 FMAs/thread,
// cross-wave reduce via LDS partials, tanh, write h back to LDS + global row.
// Raw lgkmcnt-only barriers keep the xp prefetch load and the h store
// (vmcnt traffic) off the critical path.
// ---------------------------------------------------------------------------
__global__ __launch_bounds__(256, 1) void k2_rnn(
    const float* __restrict__ Wh, float* __restrict__ XH)
{
    const int b = blockIdx.x;
    const int tid = threadIdx.x;
    const int lane = tid & 63;
    const int q = tid >> 6;

    __shared__ __align__(16) float hs[256];
    __shared__ __align__(16) float part[4][260];

    float w[4][64];
    {
        const float* wb = Wh + (size_t)(4*lane)*DIM + 64*q;
        #pragma unroll
        for (int jj = 0; jj < 4; ++jj) {
            #pragma unroll
            for (int kk = 0; kk < 64; kk += 4) {
                float4 v = *(const float4*)(wb + jj*DIM + kk);
                w[jj][kk+0]=v.x; w[jj][kk+1]=v.y; w[jj][kk+2]=v.z; w[jj][kk+3]=v.w;
            }
        }
    }

    hs[tid] = 0.0f;
    float xp_cur = XH[(size_t)b*DIM + tid];   // row (t=0)*32 + b
    asm volatile("s_waitcnt lgkmcnt(0)\n\ts_barrier" ::: "memory");

    for (int t = 0; t < TSEQ; ++t) {
        const int t1 = (t + 1 < TSEQ) ? (t + 1) : t;
        float xp_nxt = XH[((size_t)t1*NB + b)*DIM + tid];   // prefetch next step

        float accA[4] = {0.f, 0.f, 0.f, 0.f};
        float accB[4] = {0.f, 0.f, 0.f, 0.f};
        #pragma unroll
        for (int kk = 0; kk < 32; kk += 4) {
            float4 hv = *(const float4*)&hs[(q << 6) + kk];
            #pragma unroll
            for (int jj = 0; jj < 4; ++jj) {
                accA[jj] = fmaf(w[jj][kk+0], hv.x, accA[jj]);
                accA[jj] = fmaf(w[jj][kk+1], hv.y, accA[jj]);
                accA[jj] = fmaf(w[jj][kk+2], hv.z, accA[jj]);
                accA[jj] = fmaf(w[jj][kk+3], hv.w, accA[jj]);
            }
        }
        #pragma unroll
        for (int kk = 32; kk < 64; kk += 4) {
            float4 hv = *(const float4*)&hs[(q << 6) + kk];
            #pragma unroll
            for (int jj = 0; jj < 4; ++jj) {
                accB[jj] = fmaf(w[jj][kk+0], hv.x, accB[jj]);
                accB[jj] = fmaf(w[jj][kk+1], hv.y, accB[jj]);
                accB[jj] = fmaf(w[jj][kk+2], hv.z, accB[jj]);
                accB[jj] = fmaf(w[jj][kk+3], hv.w, accB[jj]);
            }
        }
        float4 pv = make_float4(accA[0]+accB[0], accA[1]+accB[1],
                                accA[2]+accB[2], accA[3]+accB[3]);
        *(float4*)&part[q][4*lane] = pv;
        asm volatile("s_waitcnt lgkmcnt(0)\n\ts_barrier" ::: "memory");

        // every thread reduces one output j = tid (stride-260 rows: conflict-free)
        float s = part[0][tid] + part[1][tid] + part[2][tid] + part[3][tid] + xp_cur;
        float hn = tanhf(s);
        hs[tid] = hn;
        XH[((size_t)t*NB + b)*DIM + tid] = hn;   // fire-and-forget store
        xp_cur = xp_nxt;
        asm volatile("s_waitcnt lgkmcnt(0)\n\ts_barrier" ::: "memory");
    }
}

// ---------------------------------------------------------------------------
// K3: in-place y = h @ Wy^T + Wy_b on d_out. Row-exclusive: WG owns 64 full
// rows (BN = 256 = full N), so in-place is safe (all A reads of a tile precede
// the barrier that precedes any C write). Column groups interleaved (64c+4tn)
// to keep LDS B reads 2-way-conflict-free.
// ---------------------------------------------------------------------------
__global__ __launch_bounds__(256) void k3_y(
    const float* __restrict__ Wy, const float* __restrict__ by,
    float* __restrict__ XH)
{
    __shared__ __align__(16) float As[32][68];
    __shared__ __align__(16) float Bs[32][264];
    const int tid = threadIdx.x;
    const int r0 = blockIdx.x * 64;
    const int tm = tid >> 4, tn = tid & 15;
    const int lr = tid >> 2;
    const int lk = (tid & 3) * 8;

    const float* arow = XH + (size_t)(r0 + lr) * DIM;
    const float* brow = Wy + (size_t)tid * DIM;

    float acc[4][4][4] = {};   // [row i][colgroup c][cc]

    for (int k0 = 0; k0 < DIM; k0 += 32) {
        float4 a0 = *(const float4*)(arow + k0 + lk);
        float4 a1 = *(const float4*)(arow + k0 + lk + 4);
        float4 wv[8];
        #pragma unroll
        for (int i = 0; i < 8; ++i) wv[i] = *(const float4*)(brow + k0 + 4*i);
        __syncthreads();
        As[lk+0][lr]=a0.x; As[lk+1][lr]=a0.y; As[lk+2][lr]=a0.z; As[lk+3][lr]=a0.w;
        As[lk+4][lr]=a1.x; As[lk+5][lr]=a1.y; As[lk+6][lr]=a1.z; As[lk+7][lr]=a1.w;
        #pragma unroll
        for (int i = 0; i < 8; ++i) {
            Bs[4*i+0][tid] = wv[i].x;
            Bs[4*i+1][tid] = wv[i].y;
            Bs[4*i+2][tid] = wv[i].z;
            Bs[4*i+3][tid] = wv[i].w;
        }
        __syncthreads();
        #pragma unroll
        for (int k = 0; k < 32; ++k) {
            float4 av = *(const float4*)&As[k][4*tm];
            float avv[4] = {av.x, av.y, av.z, av.w};
            #pragma unroll
            for (int c = 0; c < 4; ++c) {
                float4 bv = *(const float4*)&Bs[k][64*c + 4*tn];
                #pragma unroll
                for (int i = 0; i < 4; ++i) {
                    acc[i][c][0] = fmaf(avv[i], bv.x, acc[i][c][0]);
                    acc[i][c][1] = fmaf(avv[i], bv.y, acc[i][c][1]);
                    acc[i][c][2] = fmaf(avv[i], bv.z, acc[i][c][2]);
                    acc[i][c][3] = fmaf(avv[i], bv.w, acc[i][c][3]);
                }
            }
        }
    }

    float4 byv[4];
    #pragma unroll
    for (int c = 0; c < 4; ++c) byv[c] = *(const float4*)(by + 64*c + 4*tn);
    #pragma unroll
    for (int i = 0; i < 4; ++i) {
        size_t r = (size_t)(r0 + 4*tm + i);
        #pragma unroll
        for (int c = 0; c < 4; ++c) {
            float4 o = make_float4(acc[i][c][0] + byv[c].x, acc[i][c][1] + byv[c].y,
                                   acc[i][c][2] + byv[c].z, acc[i][c][3] + byv[c].w);
            *(float4*)(XH + r*DIM + 64*c + 4*tn) = o;
        }
    }
}

extern "C" void kernel_launch(void* const* d_in, const int* in_sizes, int n_in,
                              void* d_out, int out_size, void* d_ws, size_t ws_size,
                              hipStream_t stream)
{
    const float* X    = (const float*)d_in[0];
    const float* Wx_w = (const float*)d_in[1];
    const float* Wx_b = (const float*)d_in[2];
    const float* Wh_w = (const float*)d_in[3];
    const float* Wh_b = (const float*)d_in[4];
    const float* Wy_w = (const float*)d_in[5];
    const float* Wy_b = (const float*)d_in[6];
    float* out = (float*)d_out;

    // Phase 1: xp rows into d_out (row r = t*32+b), biases folded in.
    dim3 g1((TSEQ * NB) / 64, DIM / 64);
    k1_xproj<<<g1, 256, 0, stream>>>(X, Wx_w, Wx_b, Wh_b, out);

    // Phase 2: recurrence in-place (xp row -> h row).
    k2_rnn<<<NB, 256, 0, stream>>>(Wh_w, out);

    // Phase 3: y = h @ Wy^T + b in-place.
    k3_y<<<(TSEQ * NB) / 64, 256, 0, stream>>>(Wy_w, Wy_b, out);
}

// Round 4
// 3522.507 us; speedup vs baseline: 1.4187x; 1.4187x over previous
//
#include <hip/hip_runtime.h>
#include <cmath>

#define TSEQ 4096
#define NB   32
#define DIM  256

// ---------------------------------------------------------------------------
// K1: out[r,:] = X[b,t,:] @ Wx^T + (Wx_b + Wh_b), where r = t*32 + b
// ---------------------------------------------------------------------------
__global__ __launch_bounds__(256) void k1_xproj(
    const float* __restrict__ X, const float* __restrict__ Wx,
    const float* __restrict__ bx, const float* __restrict__ bh,
    float* __restrict__ out)
{
    __shared__ __align__(16) float As[32][68];
    __shared__ __align__(16) float Bs[32][68];
    const int tid = threadIdx.x;
    const int r0 = blockIdx.x * 64;
    const int n0 = blockIdx.y * 64;
    const int tm = tid >> 4, tn = tid & 15;
    const int lr = tid >> 2;
    const int lk = (tid & 3) * 8;

    const int rg = r0 + lr;
    const float* arow = X + ((size_t)(rg & 31) * TSEQ + (size_t)(rg >> 5)) * DIM;
    const float* brow = Wx + (size_t)(n0 + lr) * DIM;

    float acc[4][4] = {};

    for (int k0 = 0; k0 < DIM; k0 += 32) {
        float4 a0 = *(const float4*)(arow + k0 + lk);
        float4 a1 = *(const float4*)(arow + k0 + lk + 4);
        float4 b0 = *(const float4*)(brow + k0 + lk);
        float4 b1 = *(const float4*)(brow + k0 + lk + 4);
        __syncthreads();
        As[lk+0][lr]=a0.x; As[lk+1][lr]=a0.y; As[lk+2][lr]=a0.z; As[lk+3][lr]=a0.w;
        As[lk+4][lr]=a1.x; As[lk+5][lr]=a1.y; As[lk+6][lr]=a1.z; As[lk+7][lr]=a1.w;
        Bs[lk+0][lr]=b0.x; Bs[lk+1][lr]=b0.y; Bs[lk+2][lr]=b0.z; Bs[lk+3][lr]=b0.w;
        Bs[lk+4][lr]=b1.x; Bs[lk+5][lr]=b1.y; Bs[lk+6][lr]=b1.z; Bs[lk+7][lr]=b1.w;
        __syncthreads();
        #pragma unroll
        for (int k = 0; k < 32; ++k) {
            float4 av = *(const float4*)&As[k][4*tm];
            float4 bv = *(const float4*)&Bs[k][4*tn];
            float avv[4] = {av.x, av.y, av.z, av.w};
            float bvv[4] = {bv.x, bv.y, bv.z, bv.w};
            #pragma unroll
            for (int i = 0; i < 4; ++i)
                #pragma unroll
                for (int j = 0; j < 4; ++j)
                    acc[i][j] = fmaf(avv[i], bvv[j], acc[i][j]);
        }
    }

    float4 bxa = *(const float4*)(bx + n0 + 4*tn);
    float4 bha = *(const float4*)(bh + n0 + 4*tn);
    float bias[4] = {bxa.x + bha.x, bxa.y + bha.y, bxa.z + bha.z, bxa.w + bha.w};
    #pragma unroll
    for (int i = 0; i < 4; ++i) {
        size_t r = (size_t)(r0 + 4*tm + i);
        float4 o = make_float4(acc[i][0] + bias[0], acc[i][1] + bias[1],
                               acc[i][2] + bias[2], acc[i][3] + bias[3]);
        *(float4*)(out + r*DIM + n0 + 4*tn) = o;
    }
}

// ---------------------------------------------------------------------------
// K2: sequential recurrence, in-place on d_out.
// 512 threads = 8 waves (2/SIMD). Thread (s,j): s=tid>>8 (k-half), j=tid&255
// (output row). 128 weights/thread stay in arch VGPRs (launch_bounds(512,2)
// -> 256-VGPR cap; no AGPR round-trips like the 256-float/thread version).
// h broadcast from LDS (wave-uniform b128 reads). One LDS partial per output
// (own partial in register). Branch-free tanh via exp2+rcp. Raw lgkmcnt-only
// barriers keep the xp prefetch / h store vmem traffic off the critical path.
// ---------------------------------------------------------------------------
__global__ __launch_bounds__(512, 2) void k2_rnn(
    const float* __restrict__ Wh, float* __restrict__ XH)
{
    const int b = blockIdx.x;
    const int tid = threadIdx.x;
    const int j = tid & 255;
    const int s = tid >> 8;          // k-half: 0 or 1 (wave-uniform)

    __shared__ __align__(16) float hs[256];
    __shared__ __align__(16) float part[256];

    // Wh[j][128*s .. 128*s+127] -> 128 VGPRs
    float w[128];
    {
        const float* wb = Wh + (size_t)j * DIM + 128 * s;
        #pragma unroll
        for (int kk = 0; kk < 128; kk += 4) {
            float4 v = *(const float4*)(wb + kk);
            w[kk+0]=v.x; w[kk+1]=v.y; w[kk+2]=v.z; w[kk+3]=v.w;
        }
    }

    if (s == 0) hs[j] = 0.0f;
    float xp_cur = 0.0f;
    if (s == 0) xp_cur = XH[(size_t)b * DIM + j];      // row t=0
    asm volatile("s_waitcnt lgkmcnt(0)\n\ts_barrier" ::: "memory");

    const float* hbase = &hs[128 * s];

    for (int t = 0; t < TSEQ; ++t) {
        const int t1 = (t + 1 < TSEQ) ? (t + 1) : t;
        float xp_nxt = 0.0f;
        if (s == 0) xp_nxt = XH[((size_t)t1 * NB + b) * DIM + j];  // prefetch

        float a0 = 0.f, a1 = 0.f, a2 = 0.f, a3 = 0.f;
        #pragma unroll
        for (int kk = 0; kk < 128; kk += 16) {
            float4 h0 = *(const float4*)(hbase + kk);
            float4 h1 = *(const float4*)(hbase + kk + 4);
            float4 h2 = *(const float4*)(hbase + kk + 8);
            float4 h3 = *(const float4*)(hbase + kk + 12);
            a0 = fmaf(w[kk+ 0], h0.x, a0); a1 = fmaf(w[kk+ 1], h0.y, a1);
            a2 = fmaf(w[kk+ 2], h0.z, a2); a3 = fmaf(w[kk+ 3], h0.w, a3);
            a0 = fmaf(w[kk+ 4], h1.x, a0); a1 = fmaf(w[kk+ 5], h1.y, a1);
            a2 = fmaf(w[kk+ 6], h1.z, a2); a3 = fmaf(w[kk+ 7], h1.w, a3);
            a0 = fmaf(w[kk+ 8], h2.x, a0); a1 = fmaf(w[kk+ 9], h2.y, a1);
            a2 = fmaf(w[kk+10], h2.z, a2); a3 = fmaf(w[kk+11], h2.w, a3);
            a0 = fmaf(w[kk+12], h3.x, a0); a1 = fmaf(w[kk+13], h3.y, a1);
            a2 = fmaf(w[kk+14], h3.z, a2); a3 = fmaf(w[kk+15], h3.w, a3);
        }
        float acc = (a0 + a1) + (a2 + a3);

        if (s) part[j] = acc;        // s==1 publishes its partial
        asm volatile("s_waitcnt lgkmcnt(0)\n\ts_barrier" ::: "memory");

        if (s == 0) {
            float sum = acc + part[j] + xp_cur;
            // tanh(x) = 1 - 2/(exp(2x)+1); exp via v_exp_f32 (2^x), rcp raw.
            float e = __builtin_amdgcn_exp2f(sum * 2.8853900817779268f); // 2*log2(e)
            float r = __builtin_amdgcn_rcpf(e + 1.0f);
            float hn = fmaf(-2.0f, r, 1.0f);
            hs[j] = hn;
            XH[((size_t)t * NB + b) * DIM + j] = hn;   // fire-and-forget
        }
        xp_cur = xp_nxt;
        asm volatile("s_waitcnt lgkmcnt(0)\n\ts_barrier" ::: "memory");
    }
}

// ---------------------------------------------------------------------------
// K3: in-place y = h @ Wy^T + Wy_b on d_out (row-exclusive tiles).
// ---------------------------------------------------------------------------
__global__ __launch_bounds__(256) void k3_y(
    const float* __restrict__ Wy, const float* __restrict__ by,
    float* __restrict__ XH)
{
    __shared__ __align__(16) float As[32][68];
    __shared__ __align__(16) float Bs[32][264];
    const int tid = threadIdx.x;
    const int r0 = blockIdx.x * 64;
    const int tm = tid >> 4, tn = tid & 15;
    const int lr = tid >> 2;
    const int lk = (tid & 3) * 8;

    const float* arow = XH + (size_t)(r0 + lr) * DIM;
    const float* brow = Wy + (size_t)tid * DIM;

    float acc[4][4][4] = {};

    for (int k0 = 0; k0 < DIM; k0 += 32) {
        float4 a0 = *(const float4*)(arow + k0 + lk);
        float4 a1 = *(const float4*)(arow + k0 + lk + 4);
        float4 wv[8];
        #pragma unroll
        for (int i = 0; i < 8; ++i) wv[i] = *(const float4*)(brow + k0 + 4*i);
        __syncthreads();
        As[lk+0][lr]=a0.x; As[lk+1][lr]=a0.y; As[lk+2][lr]=a0.z; As[lk+3][lr]=a0.w;
        As[lk+4][lr]=a1.x; As[lk+5][lr]=a1.y; As[lk+6][lr]=a1.z; As[lk+7][lr]=a1.w;
        #pragma unroll
        for (int i = 0; i < 8; ++i) {
            Bs[4*i+0][tid] = wv[i].x;
            Bs[4*i+1][tid] = wv[i].y;
            Bs[4*i+2][tid] = wv[i].z;
            Bs[4*i+3][tid] = wv[i].w;
        }
        __syncthreads();
        #pragma unroll
        for (int k = 0; k < 32; ++k) {
            float4 av = *(const float4*)&As[k][4*tm];
            float avv[4] = {av.x, av.y, av.z, av.w};
            #pragma unroll
            for (int c = 0; c < 4; ++c) {
                float4 bv = *(const float4*)&Bs[k][64*c + 4*tn];
                #pragma unroll
                for (int i = 0; i < 4; ++i) {
                    acc[i][c][0] = fmaf(avv[i], bv.x, acc[i][c][0]);
                    acc[i][c][1] = fmaf(avv[i], bv.y, acc[i][c][1]);
                    acc[i][c][2] = fmaf(avv[i], bv.z, acc[i][c][2]);
                    acc[i][c][3] = fmaf(avv[i], bv.w, acc[i][c][3]);
                }
            }
        }
    }

    float4 byv[4];
    #pragma unroll
    for (int c = 0; c < 4; ++c) byv[c] = *(const float4*)(by + 64*c + 4*tn);
    #pragma unroll
    for (int i = 0; i < 4; ++i) {
        size_t r = (size_t)(r0 + 4*tm + i);
        #pragma unroll
        for (int c = 0; c < 4; ++c) {
            float4 o = make_float4(acc[i][c][0] + byv[c].x, acc[i][c][1] + byv[c].y,
                                   acc[i][c][2] + byv[c].z, acc[i][c][3] + byv[c].w);
            *(float4*)(XH + r*DIM + 64*c + 4*tn) = o;
        }
    }
}

extern "C" void kernel_launch(void* const* d_in, const int* in_sizes, int n_in,
                              void* d_out, int out_size, void* d_ws, size_t ws_size,
                              hipStream_t stream)
{
    const float* X    = (const float*)d_in[0];
    const float* Wx_w = (const float*)d_in[1];
    const float* Wx_b = (const float*)d_in[2];
    const float* Wh_w = (const float*)d_in[3];
    const float* Wh_b = (const float*)d_in[4];
    const float* Wy_w = (const float*)d_in[5];
    const float* Wy_b = (const float*)d_in[6];
    float* out = (float*)d_out;

    dim3 g1((TSEQ * NB) / 64, DIM / 64);
    k1_xproj<<<g1, 256, 0, stream>>>(X, Wx_w, Wx_b, Wh_b, out);

    k2_rnn<<<NB, 512, 0, stream>>>(Wh_w, out);

    k3_y<<<(TSEQ * NB) / 64, 256, 0, stream>>>(Wy_w, Wy_b, out);
}